// Round 4
// baseline (6908.531 us; speedup 1.0000x reference)
//
#include <hip/hip_runtime.h>
#include <hip/hip_bf16.h>
#include <cstddef>

#define THRESH 1e-6f

__device__ __forceinline__ float thrf(float x) { return x > THRESH ? x : 0.0f; }
__device__ __forceinline__ float sigm(float x) { return 1.0f / (1.0f + expf(-x)); }

// ---------------------------------------------------------------------------
// K1: fused gather+MLP GEMM.
//   emb[m][n] = thr( sum_k thr(W1[tok[m]][k]+b1[k]) * W2[k][n] + b2[n] )
// M=4096, N=256, K=512.  BM=BN=64, BK=32, 256 threads, 4x4 micro-tile.
// The W1 row-gather + b1 + threshold is fused into the A-tile staging, so no
// A1 scratch buffer is needed and W2 gets full LDS-tile reuse.
// ---------------------------------------------------------------------------
__global__ __launch_bounds__(256) void k_embed_gemm(const int* __restrict__ tok,
                                                    const float* __restrict__ W1,
                                                    const float* __restrict__ b1,
                                                    const float* __restrict__ W2,
                                                    const float* __restrict__ b2,
                                                    float* __restrict__ emb) {
    constexpr int BM = 64, BN = 64, BK = 32, K = 512, N = 256;
    __shared__ float As[BK][BM + 1];
    __shared__ float Bs[BK][BN];

    const int tid = threadIdx.x;
    const int bm = blockIdx.x * BM;
    const int bn = blockIdx.y * BN;
    const int tn = (tid & 15) * 4;
    const int tm = (tid >> 4) * 4;

    float acc[4][4] = {};

    for (int k0 = 0; k0 < K; k0 += BK) {
        // A tile: row r of tile = token bm+r; fused gather + b1 + thr
        for (int i = tid; i < BM * BK / 4; i += 256) {
            int c4 = (i & (BK / 4 - 1)) * 4;
            int r  = i / (BK / 4);
            int tv = tok[bm + r];
            float4 v  = *(const float4*)(W1 + (size_t)tv * K + k0 + c4);
            float4 bb = *(const float4*)(b1 + k0 + c4);
            As[c4 + 0][r] = thrf(v.x + bb.x);
            As[c4 + 1][r] = thrf(v.y + bb.y);
            As[c4 + 2][r] = thrf(v.z + bb.z);
            As[c4 + 3][r] = thrf(v.w + bb.w);
        }
        // B tile: W2 is (K x N) row-major
        for (int i = tid; i < BK * BN / 4; i += 256) {
            int n4 = (i & 15) * 4;
            int kk = i >> 4;
            *(float4*)&Bs[kk][n4] = *(const float4*)(W2 + (size_t)(k0 + kk) * N + bn + n4);
        }
        __syncthreads();

        for (int k = 0; k < BK; ++k) {
            float a0 = As[k][tm + 0], a1 = As[k][tm + 1];
            float a2 = As[k][tm + 2], a3 = As[k][tm + 3];
            float b0 = Bs[k][tn + 0], b1v = Bs[k][tn + 1];
            float b2v = Bs[k][tn + 2], b3v = Bs[k][tn + 3];
            acc[0][0] += a0 * b0;  acc[0][1] += a0 * b1v;
            acc[0][2] += a0 * b2v; acc[0][3] += a0 * b3v;
            acc[1][0] += a1 * b0;  acc[1][1] += a1 * b1v;
            acc[1][2] += a1 * b2v; acc[1][3] += a1 * b3v;
            acc[2][0] += a2 * b0;  acc[2][1] += a2 * b1v;
            acc[2][2] += a2 * b2v; acc[2][3] += a2 * b3v;
            acc[3][0] += a3 * b0;  acc[3][1] += a3 * b1v;
            acc[3][2] += a3 * b2v; acc[3][3] += a3 * b3v;
        }
        __syncthreads();
    }

    const float4 bv = *(const float4*)(b2 + bn + tn);
    for (int i = 0; i < 4; ++i) {
        int m = bm + tm + i;
        float4 o;
        o.x = thrf(acc[i][0] + bv.x);
        o.y = thrf(acc[i][1] + bv.y);
        o.z = thrf(acc[i][2] + bv.z);
        o.w = thrf(acc[i][3] + bv.w);
        *(float4*)(emb + (size_t)m * N + bn + tn) = o;
    }
}

// ---------------------------------------------------------------------------
// K2: one GRU timestep, x-projection fused.  grid = 128 blocks x 1024 threads
// (16 waves/CU = 4 waves/SIMD on 128 CUs -> real latency hiding; R3's 256-thr
// version ran at 1 wave/SIMD and was ~38us/step latency-bound).
// tid = kh*128 + b*4 + jl :  jl in [0,4) local j, b in [0,32), kh in [0,8)
//   j = blockIdx.x*4 + jl
//   x-part: K=256 split 8x32 ; h-part: K=512 split 8x64
// 8 partials reduced through LDS; kh==0 threads finalize gates.
// ---------------------------------------------------------------------------
__global__ __launch_bounds__(1024) void k_gru_step(const float* __restrict__ h_in,
                                                   float* __restrict__ h_out,
                                                   const float* __restrict__ emb_t, // (32,256)
                                                   const float* __restrict__ W_ih,  // (1536,256)
                                                   const float* __restrict__ W_hh,  // (1536,512)
                                                   const float* __restrict__ b_ih,
                                                   const float* __restrict__ b_hh,
                                                   int first) {
    const int tid = threadIdx.x;
    const int jl = tid & 3;
    const int b  = (tid >> 2) & 31;
    const int kh = tid >> 7;          // 0..7
    const int j  = blockIdx.x * 4 + jl;
    const int lb = b * 4 + jl;        // 0..127

    // ---- x-projection partial (32 of K=256) ----
    const float* ev  = emb_t + (size_t)b * 256 + kh * 32;
    const float* xwr = W_ih + (size_t)j * 256 + kh * 32;
    const float* xwz = W_ih + (size_t)(512 + j) * 256 + kh * 32;
    const float* xwn = W_ih + (size_t)(1024 + j) * 256 + kh * 32;
    float xr = 0.f, xz = 0.f, xn = 0.f;
#pragma unroll
    for (int k = 0; k < 32; k += 4) {
        float4 e4 = *(const float4*)(ev + k);
        float4 r4 = *(const float4*)(xwr + k);
        float4 z4 = *(const float4*)(xwz + k);
        float4 n4 = *(const float4*)(xwn + k);
        xr += e4.x * r4.x + e4.y * r4.y + e4.z * r4.z + e4.w * r4.w;
        xz += e4.x * z4.x + e4.y * z4.y + e4.z * z4.z + e4.w * z4.w;
        xn += e4.x * n4.x + e4.y * n4.y + e4.z * n4.z + e4.w * n4.w;
    }

    // ---- h-projection partial (64 of K=512) ----
    float hr = 0.f, hz = 0.f, hn = 0.f;
    if (!first) {
        const float* hv  = h_in + (size_t)b * 512 + kh * 64;
        const float* hwr = W_hh + (size_t)j * 512 + kh * 64;
        const float* hwz = W_hh + (size_t)(512 + j) * 512 + kh * 64;
        const float* hwn = W_hh + (size_t)(1024 + j) * 512 + kh * 64;
#pragma unroll
        for (int k = 0; k < 64; k += 4) {
            float4 h4 = *(const float4*)(hv + k);
            float4 r4 = *(const float4*)(hwr + k);
            float4 z4 = *(const float4*)(hwz + k);
            float4 n4 = *(const float4*)(hwn + k);
            hr += h4.x * r4.x + h4.y * r4.y + h4.z * r4.z + h4.w * r4.w;
            hz += h4.x * z4.x + h4.y * z4.y + h4.z * z4.z + h4.w * z4.w;
            hn += h4.x * n4.x + h4.y * n4.y + h4.z * n4.z + h4.w * n4.w;
        }
    }

    // ---- 8-way k-split reduction through LDS ----
    __shared__ float red[128][7][6];  // [lb][kh-1][partial]; stride 42 -> 2-way bank alias (free)
    if (kh) {
        float* rp = red[lb][kh - 1];
        rp[0] = xr; rp[1] = xz; rp[2] = xn;
        rp[3] = hr; rp[4] = hz; rp[5] = hn;
    }
    __syncthreads();

    if (kh == 0) {
#pragma unroll
        for (int q = 0; q < 7; ++q) {
            const float* rp = red[lb][q];
            xr += rp[0]; xz += rp[1]; xn += rp[2];
            hr += rp[3]; hz += rp[4]; hn += rp[5];
        }
        float r = sigm(xr + b_ih[j]        + hr + b_hh[j]);
        float z = sigm(xz + b_ih[512 + j]  + hz + b_hh[512 + j]);
        float n = tanhf(xn + b_ih[1024 + j] + r * (hn + b_hh[1024 + j]));
        float hp = first ? 0.0f : h_in[(size_t)b * 512 + j];
        h_out[(size_t)b * 512 + j] = (1.0f - z) * n + z * hp;
    }
}

// ---------------------------------------------------------------------------
// K3: head.  out[b][o] = sum_k h[b][k] * W3[k][o] + b3[o]
// ---------------------------------------------------------------------------
__global__ __launch_bounds__(256) void k_head(const float* __restrict__ h,
                                              const float* __restrict__ W3,
                                              const float* __restrict__ b3,
                                              float* __restrict__ out) {
    const int b = blockIdx.x;
    const int o = threadIdx.x;
    const float* hrow = h + (size_t)b * 512;
    float acc = b3[o];
#pragma unroll 8
    for (int k = 0; k < 512; ++k)
        acc += hrow[k] * W3[(size_t)k * 256 + o];
    out[(size_t)b * 256 + o] = acc;
}

// ---------------------------------------------------------------------------
extern "C" void kernel_launch(void* const* d_in, const int* in_sizes, int n_in,
                              void* d_out, int out_size, void* d_ws, size_t ws_size,
                              hipStream_t stream) {
    // setup_inputs() dict order:
    //   0:input 1:W1 2:b1 3:W2 4:b2 5:W_ih 6:W_hh 7:b_ih 8:b_hh 9:W3 10:b3
    const int*   tok  = (const int*)d_in[0];
    const float* W1   = (const float*)d_in[1];
    const float* b1   = (const float*)d_in[2];
    const float* W2   = (const float*)d_in[3];
    const float* b2   = (const float*)d_in[4];
    const float* W_ih = (const float*)d_in[5];
    const float* W_hh = (const float*)d_in[6];
    const float* b_ih = (const float*)d_in[7];
    const float* b_hh = (const float*)d_in[8];
    const float* W3   = (const float*)d_in[9];
    const float* b3   = (const float*)d_in[10];
    float* out = (float*)d_out;

    // workspace (floats): emb 4 MB + two h buffers (64 KB each) ~= 4.2 MB
    float* ws  = (float*)d_ws;
    float* emb = ws;                  // 4096*256
    float* h_a = ws + 1048576;        // 32*512
    float* h_b = h_a + 16384;         // 32*512

    // fused embedding MLP as a tiled GEMM (gather+thr folded into A staging)
    {
        dim3 g(4096 / 64, 256 / 64);
        k_embed_gemm<<<g, 256, 0, stream>>>(tok, W1, b1, W2, b2, emb);
    }

    // GRU scan: 128 sequential launches; 128 blocks x 1024 threads each
    // (4 waves/SIMD -> latency hidden; R3's 256-thr config was 1 wave/SIMD).
    const float* hin = h_a;  // unused at t=0 (first=1)
    float* hout = h_b;
    for (int t = 0; t < 128; ++t) {
        k_gru_step<<<128, 1024, 0, stream>>>(hin, hout, emb + (size_t)t * 32 * 256,
                                             W_ih, W_hh, b_ih, b_hh, t == 0 ? 1 : 0);
        float* tmp = (float*)hin;
        hin = hout;
        hout = tmp;
    }

    // head on final hidden state (pointed to by hin after last swap)
    k_head<<<32, 256, 0, stream>>>(hin, W3, b3, out);
}

// Round 6
// 2660.495 us; speedup vs baseline: 2.5967x; 2.5967x over previous
//
#include <hip/hip_runtime.h>
#include <hip/hip_bf16.h>
#include <cstddef>

#define THRESH 1e-6f
#define NBLK 128  // persistent scan grid; 1 block/CU on 128 of 256 CUs -> co-residency guaranteed

__device__ __forceinline__ float thrf(float x) { return x > THRESH ? x : 0.0f; }
__device__ __forceinline__ float sigm(float x) { return 1.0f / (1.0f + expf(-x)); }

// ---------------------------------------------------------------------------
// K1: fused gather+MLP GEMM.
//   emb[m][n] = thr( sum_k thr(W1[tok[m]][k]+b1[k]) * W2[k][n] + b2[n] )
// ---------------------------------------------------------------------------
__global__ __launch_bounds__(256) void k_embed_gemm(const int* __restrict__ tok,
                                                    const float* __restrict__ W1,
                                                    const float* __restrict__ b1,
                                                    const float* __restrict__ W2,
                                                    const float* __restrict__ b2,
                                                    float* __restrict__ emb) {
    constexpr int BM = 64, BN = 64, BK = 32, K = 512, N = 256;
    __shared__ float As[BK][BM + 1];
    __shared__ float Bs[BK][BN];

    const int tid = threadIdx.x;
    const int bm = blockIdx.x * BM;
    const int bn = blockIdx.y * BN;
    const int tn = (tid & 15) * 4;
    const int tm = (tid >> 4) * 4;

    float acc[4][4] = {};

    for (int k0 = 0; k0 < K; k0 += BK) {
        for (int i = tid; i < BM * BK / 4; i += 256) {
            int c4 = (i & (BK / 4 - 1)) * 4;
            int r  = i / (BK / 4);
            int tv = tok[bm + r];
            float4 v  = *(const float4*)(W1 + (size_t)tv * K + k0 + c4);
            float4 bb = *(const float4*)(b1 + k0 + c4);
            As[c4 + 0][r] = thrf(v.x + bb.x);
            As[c4 + 1][r] = thrf(v.y + bb.y);
            As[c4 + 2][r] = thrf(v.z + bb.z);
            As[c4 + 3][r] = thrf(v.w + bb.w);
        }
        for (int i = tid; i < BK * BN / 4; i += 256) {
            int n4 = (i & 15) * 4;
            int kk = i >> 4;
            *(float4*)&Bs[kk][n4] = *(const float4*)(W2 + (size_t)(k0 + kk) * N + bn + n4);
        }
        __syncthreads();

        for (int k = 0; k < BK; ++k) {
            float a0 = As[k][tm + 0], a1 = As[k][tm + 1];
            float a2 = As[k][tm + 2], a3 = As[k][tm + 3];
            float b0 = Bs[k][tn + 0], b1v = Bs[k][tn + 1];
            float b2v = Bs[k][tn + 2], b3v = Bs[k][tn + 3];
            acc[0][0] += a0 * b0;  acc[0][1] += a0 * b1v;
            acc[0][2] += a0 * b2v; acc[0][3] += a0 * b3v;
            acc[1][0] += a1 * b0;  acc[1][1] += a1 * b1v;
            acc[1][2] += a1 * b2v; acc[1][3] += a1 * b3v;
            acc[2][0] += a2 * b0;  acc[2][1] += a2 * b1v;
            acc[2][2] += a2 * b2v; acc[2][3] += a2 * b3v;
            acc[3][0] += a3 * b0;  acc[3][1] += a3 * b1v;
            acc[3][2] += a3 * b2v; acc[3][3] += a3 * b3v;
        }
        __syncthreads();
    }

    const float4 bv = *(const float4*)(b2 + bn + tn);
    for (int i = 0; i < 4; ++i) {
        int m = bm + tm + i;
        float4 o;
        o.x = thrf(acc[i][0] + bv.x);
        o.y = thrf(acc[i][1] + bv.y);
        o.z = thrf(acc[i][2] + bv.z);
        o.w = thrf(acc[i][3] + bv.w);
        *(float4*)(emb + (size_t)m * N + bn + tn) = o;
    }
}

// ---------------------------------------------------------------------------
// Device-scope grid barrier (sense-reversing).  Agent-scope fence builtin
// (__builtin_amdgcn_fence — what cg grid.sync lowers to; __hip_atomic_fence
// doesn't exist in this ROCm's headers) + agent-scope atomics give cross-XCD
// visibility of the non-atomic h stores.  Spin bail-out: a logic bug fails
// the bench instead of hanging it.
// ---------------------------------------------------------------------------
__device__ __forceinline__ void grid_barrier(unsigned* cnt, unsigned* gen) {
    __syncthreads();
    if (threadIdx.x == 0) {
        __builtin_amdgcn_fence(__ATOMIC_RELEASE, "agent");
        unsigned g = __hip_atomic_load(gen, __ATOMIC_RELAXED, __HIP_MEMORY_SCOPE_AGENT);
        unsigned t = __hip_atomic_fetch_add(cnt, 1u, __ATOMIC_ACQ_REL, __HIP_MEMORY_SCOPE_AGENT);
        if (t == NBLK - 1) {
            __hip_atomic_store(cnt, 0u, __ATOMIC_RELAXED, __HIP_MEMORY_SCOPE_AGENT);
            __hip_atomic_fetch_add(gen, 1u, __ATOMIC_RELEASE, __HIP_MEMORY_SCOPE_AGENT);
        } else {
            int spins = 0;
            while (__hip_atomic_load(gen, __ATOMIC_ACQUIRE, __HIP_MEMORY_SCOPE_AGENT) == g) {
                __builtin_amdgcn_s_sleep(1);
                if (++spins > (1 << 20)) break;  // bail out instead of hanging
            }
        }
        __builtin_amdgcn_fence(__ATOMIC_ACQUIRE, "agent");
    }
    __syncthreads();
}

// ---------------------------------------------------------------------------
// K2: persistent GRU scan.  128 blocks x 256 threads.
// Block bid owns j in {bid*4 .. bid*4+3} x gates {r,z,n} = 12 weight rows,
// staged ONCE in LDS (W_hh rows 12x512, W_ih rows 12x256; +4 pad each).
// Thread tid = ks*32 + bt*4 + rt:
//   rt in [0,4): 3 rows each (r_local = rt*3+rr)
//   bt in [0,8): 4 batch rows each (b = bt + 8m)
//   ks in [0,8): k-chunk (h: 64, x: 32)
// acc_h / acc_x kept separate (n-gate needs r * (hn + b_hh_n) with x apart).
// Per step: partials -> LDS k-reduction -> 128 threads finalize gates ->
// write h_next (global ping-pong) -> grid barrier.
// ---------------------------------------------------------------------------
__global__ __launch_bounds__(256) void k_gru_scan(const float* __restrict__ emb,   // (128,32,256)
                                                  const float* __restrict__ W_ih,  // (1536,256)
                                                  const float* __restrict__ W_hh,  // (1536,512)
                                                  const float* __restrict__ b_ih,
                                                  const float* __restrict__ b_hh,
                                                  float* __restrict__ h0,          // zeroed; also final h
                                                  float* __restrict__ h1,
                                                  unsigned* __restrict__ bar) {
    __shared__ float Whl[12][516];   // 24768 B
    __shared__ float Wxl[12][260];   // 12480 B
    __shared__ float red[8][776];    // 24832 B ; [ks][out] h-part, [ks][384+out] x-part
    // total LDS 62080 B (<64 KB)

    const int tid = threadIdx.x;
    const int bid = blockIdx.x;
    const int rt = tid & 3;
    const int bt = (tid >> 2) & 7;
    const int ks = tid >> 5;

    // ---- stage this block's 12 weight rows into LDS (once) ----
    for (int idx = tid; idx < 12 * 128; idx += 256) {       // W_hh rows, f4 granules
        int r  = idx >> 7;
        int k4 = (idx & 127) << 2;
        int row = (r >> 2) * 512 + bid * 4 + (r & 3);
        *(float4*)&Whl[r][k4] = *(const float4*)(W_hh + (size_t)row * 512 + k4);
    }
    for (int idx = tid; idx < 12 * 64; idx += 256) {        // W_ih rows
        int r  = idx >> 6;
        int k4 = (idx & 63) << 2;
        int row = (r >> 2) * 512 + bid * 4 + (r & 3);
        *(float4*)&Wxl[r][k4] = *(const float4*)(W_ih + (size_t)row * 256 + k4);
    }
    __syncthreads();

    const int khb = ks * 64;   // h k-chunk base
    const int kxb = ks * 32;   // x k-chunk base

    for (int t = 0; t < 128; ++t) {
        if (t) grid_barrier(bar, bar + 1);
        const float* hc = (t & 1) ? h1 : h0;   // t=0 reads zeroed h0
        float*       hn = (t & 1) ? h0 : h1;
        const float* et = emb + (size_t)t * 32 * 256;

        float acc_h[3][4] = {};
        float acc_x[3][4] = {};

        // ---- h-part: K-chunk of 64 ----
#pragma unroll
        for (int i = 0; i < 16; ++i) {
            int k = khb + i * 4;
            float4 w0 = *(const float4*)&Whl[rt * 3 + 0][k];
            float4 w1 = *(const float4*)&Whl[rt * 3 + 1][k];
            float4 w2 = *(const float4*)&Whl[rt * 3 + 2][k];
#pragma unroll
            for (int m = 0; m < 4; ++m) {
                float4 u = *(const float4*)(hc + (size_t)(bt + 8 * m) * 512 + k);
                acc_h[0][m] += u.x * w0.x + u.y * w0.y + u.z * w0.z + u.w * w0.w;
                acc_h[1][m] += u.x * w1.x + u.y * w1.y + u.z * w1.z + u.w * w1.w;
                acc_h[2][m] += u.x * w2.x + u.y * w2.y + u.z * w2.z + u.w * w2.w;
            }
        }
        // ---- x-part: K-chunk of 32 ----
#pragma unroll
        for (int i = 0; i < 8; ++i) {
            int k = kxb + i * 4;
            float4 w0 = *(const float4*)&Wxl[rt * 3 + 0][k];
            float4 w1 = *(const float4*)&Wxl[rt * 3 + 1][k];
            float4 w2 = *(const float4*)&Wxl[rt * 3 + 2][k];
#pragma unroll
            for (int m = 0; m < 4; ++m) {
                float4 u = *(const float4*)(et + (size_t)(bt + 8 * m) * 256 + k);
                acc_x[0][m] += u.x * w0.x + u.y * w0.y + u.z * w0.z + u.w * w0.w;
                acc_x[1][m] += u.x * w1.x + u.y * w1.y + u.z * w1.z + u.w * w1.w;
                acc_x[2][m] += u.x * w2.x + u.y * w2.y + u.z * w2.z + u.w * w2.w;
            }
        }

        // ---- k-split reduction via LDS ----
#pragma unroll
        for (int rr = 0; rr < 3; ++rr) {
            int r_local = rt * 3 + rr;
#pragma unroll
            for (int m = 0; m < 4; ++m) {
                int out = r_local * 32 + bt + 8 * m;
                red[ks][out]       = acc_h[rr][m];
                red[ks][384 + out] = acc_x[rr][m];
            }
        }
        __syncthreads();

        // ---- finalize gates: 128 threads, one (jl,b) each ----
        if (tid < 128) {
            int jl = tid >> 5, b = tid & 31;
            float sh[3], sx[3];
#pragma unroll
            for (int g = 0; g < 3; ++g) {
                int out = (g * 4 + jl) * 32 + b;
                float ah = 0.f, ax = 0.f;
#pragma unroll
                for (int q = 0; q < 8; ++q) { ah += red[q][out]; ax += red[q][384 + out]; }
                sh[g] = ah; sx[g] = ax;
            }
            int j = bid * 4 + jl;
            float r = sigm(sx[0] + b_ih[j]        + sh[0] + b_hh[j]);
            float z = sigm(sx[1] + b_ih[512 + j]  + sh[1] + b_hh[512 + j]);
            float n = tanhf(sx[2] + b_ih[1024 + j] + r * (sh[2] + b_hh[1024 + j]));
            float hp = hc[(size_t)b * 512 + j];
            hn[(size_t)b * 512 + j] = (1.0f - z) * n + z * hp;
        }
        // next iteration's red[] writes are gated by grid_barrier's syncthreads
    }
    // final h (t=127 wrote hn = h0)
}

// ---------------------------------------------------------------------------
// K3: head.  out[b][o] = sum_k h[b][k] * W3[k][o] + b3[o]
// ---------------------------------------------------------------------------
__global__ __launch_bounds__(256) void k_head(const float* __restrict__ h,
                                              const float* __restrict__ W3,
                                              const float* __restrict__ b3,
                                              float* __restrict__ out) {
    const int b = blockIdx.x;
    const int o = threadIdx.x;
    const float* hrow = h + (size_t)b * 512;
    float acc = b3[o];
#pragma unroll 8
    for (int k = 0; k < 512; ++k)
        acc += hrow[k] * W3[(size_t)k * 256 + o];
    out[(size_t)b * 256 + o] = acc;
}

// ---------------------------------------------------------------------------
extern "C" void kernel_launch(void* const* d_in, const int* in_sizes, int n_in,
                              void* d_out, int out_size, void* d_ws, size_t ws_size,
                              hipStream_t stream) {
    // setup_inputs() dict order:
    //   0:input 1:W1 2:b1 3:W2 4:b2 5:W_ih 6:W_hh 7:b_ih 8:b_hh 9:W3 10:b3
    const int*   tok  = (const int*)d_in[0];
    const float* W1   = (const float*)d_in[1];
    const float* b1   = (const float*)d_in[2];
    const float* W2   = (const float*)d_in[3];
    const float* b2   = (const float*)d_in[4];
    const float* W_ih = (const float*)d_in[5];
    const float* W_hh = (const float*)d_in[6];
    const float* b_ih = (const float*)d_in[7];
    const float* b_hh = (const float*)d_in[8];
    const float* W3   = (const float*)d_in[9];
    const float* b3   = (const float*)d_in[10];
    float* out = (float*)d_out;

    // workspace (floats): emb 4MB + h ping-pong (64KB x2) + barrier vars
    float* ws  = (float*)d_ws;
    float* emb = ws;                         // 4096*256
    float* h_a = ws + 1048576;               // 32*512
    float* h_b = h_a + 16384;                // 32*512
    unsigned* bar = (unsigned*)(h_b + 16384);  // 2 x u32

    // zero h_a, h_b and barrier counters (ws is poisoned 0xAA each launch)
    (void)hipMemsetAsync(h_a, 0, 2 * 16384 * sizeof(float) + 2 * sizeof(unsigned), stream);

    // fused embedding MLP (gather+thr folded into A staging)
    {
        dim3 g(4096 / 64, 256 / 64);
        k_embed_gemm<<<g, 256, 0, stream>>>(tok, W1, b1, W2, b2, emb);
    }

    // persistent GRU scan: weights LDS-resident, 1 launch, 127 grid barriers
    k_gru_scan<<<NBLK, 256, 0, stream>>>(emb, W_ih, W_hh, b_ih, b_hh, h_a, h_b, bar);

    // head on final hidden state (in h_a)
    k_head<<<32, 256, 0, stream>>>(h_a, W3, b3, out);
}

// Round 7
// 1398.665 us; speedup vs baseline: 4.9394x; 1.9022x over previous
//
#include <hip/hip_runtime.h>
#include <hip/hip_bf16.h>
#include <cstddef>

#define THRESH 1e-6f
#define NBLK 256        // scan grid: 1 block/CU target; 256*8 waves << 8192 capacity -> co-residency safe
#define NTHR 512        // 8 waves/block = 2 waves/SIMD (latency hiding)
#define SPIN_LIMIT (1 << 20)

__device__ __forceinline__ float thrf(float x) { return x > THRESH ? x : 0.0f; }
__device__ __forceinline__ float sigm(float x) { return 1.0f / (1.0f + expf(-x)); }
__device__ __forceinline__ float dot4(float4 a, float4 b) {
    return a.x * b.x + a.y * b.y + a.z * b.z + a.w * b.w;
}

// ---------------------------------------------------------------------------
// K1: fused gather+MLP GEMM.
//   emb[m][n] = thr( sum_k thr(W1[tok[m]][k]+b1[k]) * W2[k][n] + b2[n] )
// ---------------------------------------------------------------------------
__global__ __launch_bounds__(256) void k_embed_gemm(const int* __restrict__ tok,
                                                    const float* __restrict__ W1,
                                                    const float* __restrict__ b1,
                                                    const float* __restrict__ W2,
                                                    const float* __restrict__ b2,
                                                    float* __restrict__ emb) {
    constexpr int BM = 64, BN = 64, BK = 32, K = 512, N = 256;
    __shared__ float As[BK][BM + 1];
    __shared__ float Bs[BK][BN];

    const int tid = threadIdx.x;
    const int bm = blockIdx.x * BM;
    const int bn = blockIdx.y * BN;
    const int tn = (tid & 15) * 4;
    const int tm = (tid >> 4) * 4;

    float acc[4][4] = {};

    for (int k0 = 0; k0 < K; k0 += BK) {
        for (int i = tid; i < BM * BK / 4; i += 256) {
            int c4 = (i & (BK / 4 - 1)) * 4;
            int r  = i / (BK / 4);
            int tv = tok[bm + r];
            float4 v  = *(const float4*)(W1 + (size_t)tv * K + k0 + c4);
            float4 bb = *(const float4*)(b1 + k0 + c4);
            As[c4 + 0][r] = thrf(v.x + bb.x);
            As[c4 + 1][r] = thrf(v.y + bb.y);
            As[c4 + 2][r] = thrf(v.z + bb.z);
            As[c4 + 3][r] = thrf(v.w + bb.w);
        }
        for (int i = tid; i < BK * BN / 4; i += 256) {
            int n4 = (i & 15) * 4;
            int kk = i >> 4;
            *(float4*)&Bs[kk][n4] = *(const float4*)(W2 + (size_t)(k0 + kk) * N + bn + n4);
        }
        __syncthreads();

        for (int k = 0; k < BK; ++k) {
            float a0 = As[k][tm + 0], a1 = As[k][tm + 1];
            float a2 = As[k][tm + 2], a3 = As[k][tm + 3];
            float b0 = Bs[k][tn + 0], b1v = Bs[k][tn + 1];
            float b2v = Bs[k][tn + 2], b3v = Bs[k][tn + 3];
            acc[0][0] += a0 * b0;  acc[0][1] += a0 * b1v;
            acc[0][2] += a0 * b2v; acc[0][3] += a0 * b3v;
            acc[1][0] += a1 * b0;  acc[1][1] += a1 * b1v;
            acc[1][2] += a1 * b2v; acc[1][3] += a1 * b3v;
            acc[2][0] += a2 * b0;  acc[2][1] += a2 * b1v;
            acc[2][2] += a2 * b2v; acc[2][3] += a2 * b3v;
            acc[3][0] += a3 * b0;  acc[3][1] += a3 * b1v;
            acc[3][2] += a3 * b2v; acc[3][3] += a3 * b3v;
        }
        __syncthreads();
    }

    const float4 bv = *(const float4*)(b2 + bn + tn);
    for (int i = 0; i < 4; ++i) {
        int m = bm + tm + i;
        float4 o;
        o.x = thrf(acc[i][0] + bv.x);
        o.y = thrf(acc[i][1] + bv.y);
        o.z = thrf(acc[i][2] + bv.z);
        o.w = thrf(acc[i][3] + bv.w);
        *(float4*)(emb + (size_t)m * N + bn + tn) = o;
    }
}

// ---------------------------------------------------------------------------
// Flag-array grid barrier.
//  - arrival: each block RELEASE-stores step t to its own cacheline (flags,
//    128B apart) -> no contended RMW (R6's single fetch_add serialized 128
//    RMWs/step).
//  - block 0 wave 0 scans all 256 flags with RELAXED agent atomic loads
//    (scope bits bypass the non-coherent L1/L2; RELAXED avoids the per-poll
//    L2 invalidate that made R6's ACQUIRE-spin a cross-XCD inv storm),
//    then RELEASE-stores gen = t.
//  - waiters poll gen RELAXED, then ONE acquire fence.
// Spin bail-outs keep a logic bug a visible failure, not a hang.
// ---------------------------------------------------------------------------
__device__ __forceinline__ void gbar(unsigned* __restrict__ flags,
                                     unsigned* __restrict__ gen, unsigned t) {
    __syncthreads();
    if (blockIdx.x == 0) {
        if (threadIdx.x == 0)
            __hip_atomic_store(&flags[0], t, __ATOMIC_RELEASE, __HIP_MEMORY_SCOPE_AGENT);
        if (threadIdx.x < 64) {
            const int base = threadIdx.x * 4;
            int spins = 0;
            bool ok;
            do {
                ok = true;
#pragma unroll
                for (int i = 0; i < 4; ++i) {
                    unsigned f = __hip_atomic_load(&flags[(base + i) * 32],
                                                   __ATOMIC_RELAXED, __HIP_MEMORY_SCOPE_AGENT);
                    ok &= (f >= t);
                }
                if (ok) break;
                __builtin_amdgcn_s_sleep(1);
            } while (++spins < SPIN_LIMIT);
            // wave reconverges only when every lane's 4 flags arrived
            if (threadIdx.x == 0) {
                __builtin_amdgcn_fence(__ATOMIC_ACQUIRE, "agent");
                __hip_atomic_store(gen, t, __ATOMIC_RELEASE, __HIP_MEMORY_SCOPE_AGENT);
            }
        }
    } else {
        if (threadIdx.x == 0) {
            __hip_atomic_store(&flags[blockIdx.x * 32], t, __ATOMIC_RELEASE, __HIP_MEMORY_SCOPE_AGENT);
            int spins = 0;
            while (__hip_atomic_load(gen, __ATOMIC_RELAXED, __HIP_MEMORY_SCOPE_AGENT) < t) {
                __builtin_amdgcn_s_sleep(1);
                if (++spins > SPIN_LIMIT) break;
            }
            __builtin_amdgcn_fence(__ATOMIC_ACQUIRE, "agent");
        }
    }
    __syncthreads();
}

// ---------------------------------------------------------------------------
// K2: persistent GRU scan.  256 blocks x 512 threads (2 waves/SIMD).
// Block bid owns j in {bid*2, bid*2+1} x 3 gates = 6 weight rows in LDS.
// Thread tid: rt = tid&1 (which j), bt = (tid>>1)&15 (b = bt, bt+16),
//             ks = tid>>5 in [0,16)  (h chunk 32, x chunk 16).
// Pipeline: acc_x(t+1) (emb-only, barrier-independent) is computed AFTER
// writing h(t), overlapping other blocks' barrier arrival; carried in regs
// across the barrier.  Critical path per step = barrier + h loads + h-FMAs
// + LDS reduce + gates.
// ---------------------------------------------------------------------------
__global__ __launch_bounds__(NTHR) void k_gru_scan(const float* __restrict__ emb,   // (128,32,256)
                                                   const float* __restrict__ W_ih,  // (1536,256)
                                                   const float* __restrict__ W_hh,  // (1536,512)
                                                   const float* __restrict__ b_ih,
                                                   const float* __restrict__ b_hh,
                                                   float* __restrict__ h0,          // zeroed; final h
                                                   float* __restrict__ h1,
                                                   unsigned* __restrict__ flags,
                                                   unsigned* __restrict__ gen) {
    __shared__ __align__(16) float Whl[6][516];    // 12384 B
    __shared__ __align__(16) float Wxl[6][260];    //  6240 B
    __shared__ __align__(16) float red_h[16][208]; // 13312 B ; stride 208: ks-lane bank shift 16 -> <=2-way
    __shared__ __align__(16) float red_x[16][208]; // 13312 B
    __shared__ float bsh[6], bsx[6];

    const int tid = threadIdx.x;
    const int bid = blockIdx.x;
    const int rt = tid & 1;
    const int bt = (tid >> 1) & 15;
    const int ks = tid >> 5;        // 0..15
    const int khb = ks * 32;
    const int kxb = ks * 16;

    // ---- stage 6 weight rows + biases (once) ----
    for (int idx = tid; idx < 6 * 128; idx += NTHR) {
        int r = idx >> 7, k4 = (idx & 127) << 2;
        int row = (r >> 1) * 512 + bid * 2 + (r & 1);
        *(float4*)&Whl[r][k4] = *(const float4*)(W_hh + (size_t)row * 512 + k4);
    }
    for (int idx = tid; idx < 6 * 64; idx += NTHR) {
        int r = idx >> 6, k4 = (idx & 63) << 2;
        int row = (r >> 1) * 512 + bid * 2 + (r & 1);
        *(float4*)&Wxl[r][k4] = *(const float4*)(W_ih + (size_t)row * 256 + k4);
    }
    if (tid < 6) {
        int row = (tid >> 1) * 512 + bid * 2 + (tid & 1);
        bsh[tid] = b_hh[row];
        bsx[tid] = b_ih[row];
    }
    __syncthreads();

    // ---- x-partials for t=0 ----
    float acc_x[3][2];
    {
        const float* et = emb;
        const float* e0 = et + (size_t)bt * 256 + kxb;
        const float* e1 = et + (size_t)(bt + 16) * 256 + kxb;
        acc_x[0][0] = acc_x[0][1] = acc_x[1][0] = acc_x[1][1] = acc_x[2][0] = acc_x[2][1] = 0.f;
#pragma unroll
        for (int i = 0; i < 4; ++i) {
            int k = kxb + i * 4;
            float4 w0 = *(const float4*)&Wxl[rt][k];
            float4 w1 = *(const float4*)&Wxl[2 + rt][k];
            float4 w2 = *(const float4*)&Wxl[4 + rt][k];
            float4 u0 = *(const float4*)(e0 + i * 4);
            float4 u1 = *(const float4*)(e1 + i * 4);
            acc_x[0][0] += dot4(u0, w0); acc_x[0][1] += dot4(u1, w0);
            acc_x[1][0] += dot4(u0, w1); acc_x[1][1] += dot4(u1, w1);
            acc_x[2][0] += dot4(u0, w2); acc_x[2][1] += dot4(u1, w2);
        }
    }

    for (int t = 0; t < 128; ++t) {
        if (t) gbar(flags, gen, (unsigned)t);
        const float* hc = (t & 1) ? h1 : h0;   // t=0 reads zeroed h0
        float*       hn = (t & 1) ? h0 : h1;

        // early h_prev load for the 64 finalize threads (post-barrier = safe)
        float hp = 0.f;
        if (tid < 64)
            hp = hc[(size_t)(tid & 31) * 512 + bid * 2 + (tid >> 5)];

        // ---- h-partials: chunk of 32 ----
        float acc_h[3][2] = {};
        const float* hb0 = hc + (size_t)bt * 512 + khb;
        const float* hb1 = hc + (size_t)(bt + 16) * 512 + khb;
#pragma unroll
        for (int i = 0; i < 8; ++i) {
            int k = khb + i * 4;
            float4 w0 = *(const float4*)&Whl[rt][k];
            float4 w1 = *(const float4*)&Whl[2 + rt][k];
            float4 w2 = *(const float4*)&Whl[4 + rt][k];
            float4 u0 = *(const float4*)(hb0 + i * 4);
            float4 u1 = *(const float4*)(hb1 + i * 4);
            acc_h[0][0] += dot4(u0, w0); acc_h[0][1] += dot4(u1, w0);
            acc_h[1][0] += dot4(u0, w1); acc_h[1][1] += dot4(u1, w1);
            acc_h[2][0] += dot4(u0, w2); acc_h[2][1] += dot4(u1, w2);
        }

        // ---- write partials (acc_x carried from previous iteration) ----
#pragma unroll
        for (int g = 0; g < 3; ++g) {
            int r = g * 2 + rt;
#pragma unroll
            for (int m = 0; m < 2; ++m) {
                int out = r * 32 + bt + 16 * m;
                red_h[ks][out] = acc_h[g][m];
                red_x[ks][out] = acc_x[g][m];
            }
        }
        __syncthreads();

        // ---- stage 1: reduce 16 k-partials (384 threads, 1 column each) ----
        if (tid < 384) {
            int arr = tid >= 192;
            int out = arr ? tid - 192 : tid;
            float (*A)[208] = arr ? red_x : red_h;
            float s = 0.f;
#pragma unroll
            for (int q = 0; q < 16; ++q) s += A[q][out];
            A[0][out] = s;
        }
        __syncthreads();

        // ---- stage 2: gates (64 threads: jl = tid>>5, b = tid&31) ----
        if (tid < 64) {
            int jl = tid >> 5, b = tid & 31;
            float sh0 = red_h[0][(0 + jl) * 32 + b], sx0 = red_x[0][(0 + jl) * 32 + b];
            float sh1 = red_h[0][(2 + jl) * 32 + b], sx1 = red_x[0][(2 + jl) * 32 + b];
            float sh2 = red_h[0][(4 + jl) * 32 + b], sx2 = red_x[0][(4 + jl) * 32 + b];
            float r = sigm(sx0 + bsx[jl]     + sh0 + bsh[jl]);
            float z = sigm(sx1 + bsx[2 + jl] + sh1 + bsh[2 + jl]);
            float n = tanhf(sx2 + bsx[4 + jl] + r * (sh2 + bsh[4 + jl]));
            hn[(size_t)b * 512 + bid * 2 + jl] = (1.0f - z) * n + z * hp;
        }

        // ---- off-critical-path: x-partials for t+1 (emb only) ----
        if (t < 127) {
            const float* et = emb + (size_t)(t + 1) * 32 * 256;
            const float* e0 = et + (size_t)bt * 256 + kxb;
            const float* e1 = et + (size_t)(bt + 16) * 256 + kxb;
            acc_x[0][0] = acc_x[0][1] = acc_x[1][0] = acc_x[1][1] = acc_x[2][0] = acc_x[2][1] = 0.f;
#pragma unroll
            for (int i = 0; i < 4; ++i) {
                int k = kxb + i * 4;
                float4 w0 = *(const float4*)&Wxl[rt][k];
                float4 w1 = *(const float4*)&Wxl[2 + rt][k];
                float4 w2 = *(const float4*)&Wxl[4 + rt][k];
                float4 u0 = *(const float4*)(e0 + i * 4);
                float4 u1 = *(const float4*)(e1 + i * 4);
                acc_x[0][0] += dot4(u0, w0); acc_x[0][1] += dot4(u1, w0);
                acc_x[1][0] += dot4(u0, w1); acc_x[1][1] += dot4(u1, w1);
                acc_x[2][0] += dot4(u0, w2); acc_x[2][1] += dot4(u1, w2);
            }
        }
        // next-iter red writes are gated by gbar's entry __syncthreads
    }
    // final h in h0 (t=127 wrote hn = h0)
}

// ---------------------------------------------------------------------------
// K3: head.  out[b][o] = sum_k h[b][k] * W3[k][o] + b3[o]
// ---------------------------------------------------------------------------
__global__ __launch_bounds__(256) void k_head(const float* __restrict__ h,
                                              const float* __restrict__ W3,
                                              const float* __restrict__ b3,
                                              float* __restrict__ out) {
    const int b = blockIdx.x;
    const int o = threadIdx.x;
    const float* hrow = h + (size_t)b * 512;
    float acc = b3[o];
#pragma unroll 8
    for (int k = 0; k < 512; ++k)
        acc += hrow[k] * W3[(size_t)k * 256 + o];
    out[(size_t)b * 256 + o] = acc;
}

// ---------------------------------------------------------------------------
extern "C" void kernel_launch(void* const* d_in, const int* in_sizes, int n_in,
                              void* d_out, int out_size, void* d_ws, size_t ws_size,
                              hipStream_t stream) {
    // setup_inputs() dict order:
    //   0:input 1:W1 2:b1 3:W2 4:b2 5:W_ih 6:W_hh 7:b_ih 8:b_hh 9:W3 10:b3
    const int*   tok  = (const int*)d_in[0];
    const float* W1   = (const float*)d_in[1];
    const float* b1   = (const float*)d_in[2];
    const float* W2   = (const float*)d_in[3];
    const float* b2   = (const float*)d_in[4];
    const float* W_ih = (const float*)d_in[5];
    const float* W_hh = (const float*)d_in[6];
    const float* b_ih = (const float*)d_in[7];
    const float* b_hh = (const float*)d_in[8];
    const float* W3   = (const float*)d_in[9];
    const float* b3   = (const float*)d_in[10];
    float* out = (float*)d_out;

    // workspace (floats): emb 4MB + h ping-pong + flags(256x32 u32) + gen
    float* ws  = (float*)d_ws;
    float* emb = ws;                          // 4096*256
    float* h_a = ws + 1048576;                // 32*512
    float* h_b = h_a + 16384;                 // 32*512
    unsigned* flags = (unsigned*)(h_b + 16384);  // 8192 u32 (256 * 32)
    unsigned* gen   = flags + 8192;              // 1 u32 (+ padding)

    // zero h_a, h_b, flags, gen (ws is poisoned 0xAA before every launch)
    (void)hipMemsetAsync(h_a, 0, 2 * 16384 * sizeof(float) + 8192 * sizeof(unsigned) + 64, stream);

    // fused embedding MLP (gather+thr folded into A staging)
    {
        dim3 g(4096 / 64, 256 / 64);
        k_embed_gemm<<<g, 256, 0, stream>>>(tok, W1, b1, W2, b2, emb);
    }

    // persistent GRU scan: weights LDS-resident, 1 launch, 127 flag barriers
    k_gru_scan<<<NBLK, NTHR, 0, stream>>>(emb, W_ih, W_hh, b_ih, b_hh,
                                          h_a, h_b, flags, gen);

    // head on final hidden state (in h_a)
    k_head<<<32, 256, 0, stream>>>(h_a, W3, b3, out);
}